// Round 1
// baseline (102.493 us; speedup 1.0000x reference)
//
#include <hip/hip_runtime.h>
#include <hip/hip_bf16.h>

#define K 16
#define Bn 1024
#define Tn 512
#define START_ID 14
#define STOP_ID 15
#define LN2 0.69314718055994530942f
#define NCH 8          // chunks per sequence (one block = one sequence)
#define CL 64          // chunk length == wave size; threadIdx.x == t

typedef float f32x4 __attribute__((ext_vector_type(4)));
typedef short s16x4 __attribute__((ext_vector_type(4)));

// f32x4 -> bf16x4 via native casts: compiler emits 2x v_cvt_pk_bf16_f32
// (RNE). Replaces the old 6-VALU half-up pack (4 adds + 2 v_perm_b32);
// also shortens the C -> next-mfma dependency path from 2 VALU levels to 1.
static __device__ __forceinline__ s16x4 pack_bf16x4(float a, float b, float c, float d) {
    typedef __bf16 bf16x4v __attribute__((ext_vector_type(4)));
    bf16x4v t;
    t[0] = (__bf16)a; t[1] = (__bf16)b; t[2] = (__bf16)c; t[3] = (__bf16)d;
    union { bf16x4v bv; s16x4 sv; } u; u.bv = t;
    return u.sv;
}

// ---------------------------------------------------------------------------
// Structure identical to the validated R8/R10 kernel (best of 5 structural
// variants; per-launch cost pinned at 23.74 us by controlled N=4 measurement).
// One block (8 waves) per sequence; wave c evolves chunk c (64 steps) of the
// 16x16 linear-space transfer matrix P <- (D_t E) P, one mfma/step, exp(h)
// folded into the A-operand; per-column pow2 rescale every 8 steps (pend at
// r==3, applied at the next sub-block's B-pack); gold fused (1 gather/thread);
// P/esum/gold -> LDS -> wave 0 combines -> res[b] = fwd_b - gold_b.
// This round's only change: bf16 packing via v_cvt_pk_bf16_f32 (native casts)
// instead of the 6-VALU hand-rolled half-up pack. Dual-chain (R9/R11) and
// CL=128 (R7) variants measured WORSE (34/28 us).
// ---------------------------------------------------------------------------
__global__ __launch_bounds__(512, 8) void crf_all(
    const float* __restrict__ h, const int* __restrict__ y,
    const float* __restrict__ trans, float* __restrict__ res)
{
    __shared__ float Pl[NCH][16][16];   // [chunk][row][col]
    __shared__ float El[NCH][16];       // per-column exponent sums
    __shared__ float Gl[NCH];           // per-wave gold partials

    int tid  = threadIdx.x;             // == t
    int lane = tid & 63;
    int c    = tid >> 6;                // wave id == chunk id
    int b    = blockIdx.x;
    int s = lane & 15, q = lane >> 4;

    const int* yseq = y + (size_t)b * Tn;
    int yt = yseq[tid];
    unsigned long long bal = __ballot(yt != 0);
    int nv = __popcll(bal);             // valid steps in this chunk (prefix)

    // ---- gold: one (b,t) per thread; also pre-warms L2 ----
    const float* hseq = h + ((size_t)b * Tn) * K;
    float g = 0.f;
    if (yt != 0) {
        int yp = (tid == 0) ? START_ID : yseq[tid - 1];
        g = hseq[(size_t)tid * K + yt] + trans[yt * K + yp];
        bool last = (tid == Tn - 1) || (yseq[tid + 1] == 0);
        if (last) g += trans[STOP_ID * K + yt];
    }
#pragma unroll
    for (int off = 32; off; off >>= 1) g += __shfl_xor(g, off, 64);
    if (lane == 0) Gl[c] = g;

    // ---- chain ----
    float E0[4];
#pragma unroll
    for (int r = 0; r < 4; ++r)
        E0[r] = __expf(trans[s * K + 4 * q + r]);   // exp(-10000) -> 0

    f32x4 P;
    s16x4 bfrag;
#pragma unroll
    for (int r = 0; r < 4; ++r) {
        P[r] = (4 * q + r == s) ? 1.0f : 0.0f;
        ((short*)&bfrag)[r] = (4 * q + r == s) ? (short)0x3F80 : (short)0;
    }

    int esum = 0, pend = 0;
    const float* hcs = hseq + (size_t)c * CL * K + s;

    float hcur[8], hnxt[8];
#pragma unroll
    for (int r = 0; r < 8; ++r) hcur[r] = hcs[(size_t)r * K];

    for (int sb = 0; sb < CL / 8; ++sb) {
        int base = sb * 8;
        if (base >= nv) break;                 // wave-uniform
        int n = nv - base; if (n > 8) n = 8;

        esum += pend;
        float sc = __uint_as_float((unsigned)(127 - pend) << 23); // exact 2^-pend
        pend = 0;
        P[0] *= sc; P[1] *= sc; P[2] *= sc; P[3] *= sc;
        bfrag = pack_bf16x4(P[0], P[1], P[2], P[3]);

        float es[8];
#pragma unroll
        for (int r = 0; r < 8; ++r) es[r] = __expf(hcur[r]);
#pragma unroll
        for (int r = 0; r < 8; ++r) {          // depth-1 prefetch (clamped)
            int tt = base + 8 + r; tt = tt > CL - 1 ? CL - 1 : tt;
            hnxt[r] = hcs[(size_t)tt * K];
        }
#pragma unroll
        for (int r = 0; r < 8; ++r) {
            if (r >= n) break;                 // wave-uniform
            s16x4 afrag = pack_bf16x4(es[r] * E0[0], es[r] * E0[1],
                                      es[r] * E0[2], es[r] * E0[3]);
            f32x4 C = __builtin_amdgcn_mfma_f32_16x16x16bf16_1k(
                afrag, bfrag, (f32x4){0.f, 0.f, 0.f, 0.f}, 0, 0, 0);
            if (r == 3) {                      // per-column max -> pending 2^e
                float m4 = fmaxf(fmaxf(C[0], C[1]), fmaxf(C[2], C[3]));
                m4 = fmaxf(m4, __shfl_xor(m4, 16, 64));
                m4 = fmaxf(m4, __shfl_xor(m4, 32, 64));
                int e = (int)(__float_as_uint(m4) >> 23) - 127;
                pend = e < -126 ? -126 : (e > 126 ? 126 : e);
            }
            bfrag = pack_bf16x4(C[0], C[1], C[2], C[3]);
            P = C;
        }
#pragma unroll
        for (int r = 0; r < 8; ++r) hcur[r] = hnxt[r];
    }

    // publish chunk result (column s, rows 4q+r)
#pragma unroll
    for (int r = 0; r < 4; ++r)
        Pl[c][4 * q + r][s] = P[r];
    if (q == 0) El[c][s] = (float)esum;
    __syncthreads();

    // ---- combine (wave 0): alpha = e_START; alpha' = P~ * ldexp(w) ----
    if (c == 0) {
        int j = s;
        float ap[4];
#pragma unroll
        for (int r = 0; r < 4; ++r) ap[r] = (4 * q + r == START_ID) ? 1.0f : 0.0f;
        float ls = 0.f;

#pragma unroll
        for (int cc = 0; cc < NCH; ++cc) {
            f32x4 Pr  = *(const f32x4*)&Pl[cc][j][4 * q];
            f32x4 Erv = *(const f32x4*)&El[cc][4 * q];
            float me = fmaxf(fmaxf(Erv[0], Erv[1]), fmaxf(Erv[2], Erv[3]));
            me = fmaxf(me, __shfl_xor(me, 16, 64));
            me = fmaxf(me, __shfl_xor(me, 32, 64));
            float w0 = ldexpf(ap[0], (int)(Erv[0] - me));
            float w1 = ldexpf(ap[1], (int)(Erv[1] - me));
            float w2 = ldexpf(ap[2], (int)(Erv[2] - me));
            float w3 = ldexpf(ap[3], (int)(Erv[3] - me));
            float acc = Pr[0]*w0 + Pr[1]*w1 + Pr[2]*w2 + Pr[3]*w3;
            acc += __shfl_xor(acc, 16, 64);
            acc += __shfl_xor(acc, 32, 64);    // alpha'[j] at every lane
            float mj = acc;
#pragma unroll
            for (int off = 1; off < 16; off <<= 1)
                mj = fmaxf(mj, __shfl_xor(mj, off, 64));
            ls += me * LN2 + __logf(mj);
            float an = acc * (1.0f / mj);
#pragma unroll
            for (int r = 0; r < 4; ++r)
                ap[r] = __shfl(an, q * 4 + r, 16);
        }

        float part = 0.f;
#pragma unroll
        for (int r = 0; r < 4; ++r)
            part += ap[r] * __expf(trans[STOP_ID * K + 4 * q + r]);
        part += __shfl_xor(part, 16, 64);
        part += __shfl_xor(part, 32, 64);
        if (lane == 0) {
            float gold = Gl[0] + Gl[1] + Gl[2] + Gl[3]
                       + Gl[4] + Gl[5] + Gl[6] + Gl[7];
            res[b] = ls + __logf(part) - gold;
        }
    }
}

// ---------------------------------------------------------------------------
// K2: one block reduces 1024 per-sequence (fwd - gold) values, publishes mean.
// ---------------------------------------------------------------------------
__global__ __launch_bounds__(256) void crf_final(
    const float* __restrict__ res, float* __restrict__ out)
{
    int t = threadIdx.x;
    float v = 0.f;
#pragma unroll
    for (int k2 = 0; k2 < 4; ++k2) v += res[t + 256 * k2];
#pragma unroll
    for (int off = 32; off; off >>= 1) v += __shfl_xor(v, off, 64);
    __shared__ float red[4];
    if ((t & 63) == 0) red[t >> 6] = v;
    __syncthreads();
    if (t == 0) out[0] = (red[0] + red[1] + red[2] + red[3]) * (1.0f / Bn);
}

extern "C" void kernel_launch(void* const* d_in, const int* in_sizes, int n_in,
                              void* d_out, int out_size, void* d_ws, size_t ws_size,
                              hipStream_t stream)
{
    const float* h     = (const float*)d_in[0];
    const int*   y     = (const int*)d_in[1];
    const float* trans = (const float*)d_in[3];
    float* out = (float*)d_out;
    float* res = (float*)d_ws;          // 1024 floats

    crf_all<<<Bn, 512, 0, stream>>>(h, y, trans, res);
    crf_final<<<1, 256, 0, stream>>>(res, out);
}

// Round 2
// 101.855 us; speedup vs baseline: 1.0063x; 1.0063x over previous
//
#include <hip/hip_runtime.h>
#include <hip/hip_bf16.h>

#define K 16
#define Bn 1024
#define Tn 512
#define START_ID 14
#define STOP_ID 15
#define LN2 0.69314718055994530942f
#define NCH 8          // chunks per sequence (one block = one sequence)
#define CL 64          // chunk length == wave size; threadIdx.x == t

typedef float f32x4 __attribute__((ext_vector_type(4)));
typedef short s16x4 __attribute__((ext_vector_type(4)));
typedef __bf16 bf16x4 __attribute__((ext_vector_type(4)));

// f32x4 -> bf16x4 as a single vector convert: LLVM lowers this to exactly
// 2x v_cvt_pk_bf16_f32 (RNE). (R1's element-wise casts may not have fused.)
static __device__ __forceinline__ s16x4 pack4(f32x4 v) {
    union { bf16x4 b; s16x4 s; } u;
    u.b = __builtin_convertvector(v, bf16x4);
    return u.s;
}

// ---------------------------------------------------------------------------
// Structure identical to the validated R8/R10 kernel (best of 5 structural
// variants; per-launch cost pinned at 23.74 us by controlled N=4 measurement).
// One block (8 waves) per sequence; wave c evolves chunk c (64 steps) of the
// 16x16 linear-space transfer matrix P <- (D_t E) P, one mfma/step, exp(h)
// folded into the A-operand; per-column pow2 rescale every 8 steps; gold
// fused; P/esum/gold -> LDS -> wave 0 combines -> res[b] = fwd_b - gold_b.
// This round: all chain f32 math expressed as f32x4 vector ops so the
// compiler can select packed-FP32 VALU (v_pk_mul_f32) and paired
// v_cvt_pk_bf16_f32 — per-step chain VALU ~14 -> ~7.
// ---------------------------------------------------------------------------
__global__ __launch_bounds__(512, 8) void crf_all(
    const float* __restrict__ h, const int* __restrict__ y,
    const float* __restrict__ trans, float* __restrict__ res)
{
    __shared__ float Pl[NCH][16][16];   // [chunk][row][col]
    __shared__ float El[NCH][16];       // per-column exponent sums
    __shared__ float Gl[NCH];           // per-wave gold partials

    int tid  = threadIdx.x;             // == t
    int lane = tid & 63;
    int c    = tid >> 6;                // wave id == chunk id
    int b    = blockIdx.x;
    int s = lane & 15, q = lane >> 4;

    const int* yseq = y + (size_t)b * Tn;
    int yt = yseq[tid];
    unsigned long long bal = __ballot(yt != 0);
    int nv = __popcll(bal);             // valid steps in this chunk (prefix)

    // ---- gold: one (b,t) per thread; also pre-warms L2 ----
    const float* hseq = h + ((size_t)b * Tn) * K;
    float g = 0.f;
    if (yt != 0) {
        int yp = (tid == 0) ? START_ID : yseq[tid - 1];
        g = hseq[(size_t)tid * K + yt] + trans[yt * K + yp];
        bool last = (tid == Tn - 1) || (yseq[tid + 1] == 0);
        if (last) g += trans[STOP_ID * K + yt];
    }
#pragma unroll
    for (int off = 32; off; off >>= 1) g += __shfl_xor(g, off, 64);
    if (lane == 0) Gl[c] = g;

    // ---- chain ----
    f32x4 E0v;
#pragma unroll
    for (int r = 0; r < 4; ++r)
        E0v[r] = __expf(trans[s * K + 4 * q + r]);   // exp(-10000) -> 0

    f32x4 P;
    s16x4 bfrag;
#pragma unroll
    for (int r = 0; r < 4; ++r) {
        P[r] = (4 * q + r == s) ? 1.0f : 0.0f;
        ((short*)&bfrag)[r] = (4 * q + r == s) ? (short)0x3F80 : (short)0;
    }

    int esum = 0, pend = 0;
    const float* hcs = hseq + (size_t)c * CL * K + s;

    float hcur[8], hnxt[8];
#pragma unroll
    for (int r = 0; r < 8; ++r) hcur[r] = hcs[(size_t)r * K];

    for (int sb = 0; sb < CL / 8; ++sb) {
        int base = sb * 8;
        if (base >= nv) break;                 // wave-uniform
        int n = nv - base; if (n > 8) n = 8;

        esum += pend;
        float sc = __uint_as_float((unsigned)(127 - pend) << 23); // exact 2^-pend
        pend = 0;
        P *= sc;                                // 2x v_pk_mul_f32
        bfrag = pack4(P);                       // 2x v_cvt_pk_bf16_f32

        float es[8];
#pragma unroll
        for (int r = 0; r < 8; ++r) es[r] = __expf(hcur[r]);
#pragma unroll
        for (int r = 0; r < 8; ++r) {          // depth-1 prefetch (clamped)
            int tt = base + 8 + r; tt = tt > CL - 1 ? CL - 1 : tt;
            hnxt[r] = hcs[(size_t)tt * K];
        }
#pragma unroll
        for (int r = 0; r < 8; ++r) {
            if (r >= n) break;                 // wave-uniform
            f32x4 av = E0v * es[r];            // 2x v_pk_mul_f32
            s16x4 afrag = pack4(av);           // 2x v_cvt_pk_bf16_f32
            f32x4 C = __builtin_amdgcn_mfma_f32_16x16x16bf16_1k(
                afrag, bfrag, (f32x4){0.f, 0.f, 0.f, 0.f}, 0, 0, 0);
            if (r == 3) {                      // per-column max -> pending 2^e
                float m4 = fmaxf(fmaxf(C[0], C[1]), fmaxf(C[2], C[3]));
                m4 = fmaxf(m4, __shfl_xor(m4, 16, 64));
                m4 = fmaxf(m4, __shfl_xor(m4, 32, 64));
                int e = (int)(__float_as_uint(m4) >> 23) - 127;
                pend = e < -126 ? -126 : (e > 126 ? 126 : e);
            }
            bfrag = pack4(C);                  // 2x v_cvt_pk_bf16_f32
            P = C;
        }
#pragma unroll
        for (int r = 0; r < 8; ++r) hcur[r] = hnxt[r];
    }

    // publish chunk result (column s, rows 4q+r)
#pragma unroll
    for (int r = 0; r < 4; ++r)
        Pl[c][4 * q + r][s] = P[r];
    if (q == 0) El[c][s] = (float)esum;
    __syncthreads();

    // ---- combine (wave 0): alpha = e_START; alpha' = P~ * ldexp(w) ----
    if (c == 0) {
        int j = s;
        float ap[4];
#pragma unroll
        for (int r = 0; r < 4; ++r) ap[r] = (4 * q + r == START_ID) ? 1.0f : 0.0f;
        float ls = 0.f;

#pragma unroll
        for (int cc = 0; cc < NCH; ++cc) {
            f32x4 Pr  = *(const f32x4*)&Pl[cc][j][4 * q];
            f32x4 Erv = *(const f32x4*)&El[cc][4 * q];
            float me = fmaxf(fmaxf(Erv[0], Erv[1]), fmaxf(Erv[2], Erv[3]));
            me = fmaxf(me, __shfl_xor(me, 16, 64));
            me = fmaxf(me, __shfl_xor(me, 32, 64));
            float w0 = ldexpf(ap[0], (int)(Erv[0] - me));
            float w1 = ldexpf(ap[1], (int)(Erv[1] - me));
            float w2 = ldexpf(ap[2], (int)(Erv[2] - me));
            float w3 = ldexpf(ap[3], (int)(Erv[3] - me));
            float acc = Pr[0]*w0 + Pr[1]*w1 + Pr[2]*w2 + Pr[3]*w3;
            acc += __shfl_xor(acc, 16, 64);
            acc += __shfl_xor(acc, 32, 64);    // alpha'[j] at every lane
            float mj = acc;
#pragma unroll
            for (int off = 1; off < 16; off <<= 1)
                mj = fmaxf(mj, __shfl_xor(mj, off, 64));
            ls += me * LN2 + __logf(mj);
            float an = acc * (1.0f / mj);
#pragma unroll
            for (int r = 0; r < 4; ++r)
                ap[r] = __shfl(an, q * 4 + r, 16);
        }

        float part = 0.f;
#pragma unroll
        for (int r = 0; r < 4; ++r)
            part += ap[r] * __expf(trans[STOP_ID * K + 4 * q + r]);
        part += __shfl_xor(part, 16, 64);
        part += __shfl_xor(part, 32, 64);
        if (lane == 0) {
            float gold = Gl[0] + Gl[1] + Gl[2] + Gl[3]
                       + Gl[4] + Gl[5] + Gl[6] + Gl[7];
            res[b] = ls + __logf(part) - gold;
        }
    }
}

// ---------------------------------------------------------------------------
// K2: one block reduces 1024 per-sequence (fwd - gold) values, publishes mean.
// ---------------------------------------------------------------------------
__global__ __launch_bounds__(256) void crf_final(
    const float* __restrict__ res, float* __restrict__ out)
{
    int t = threadIdx.x;
    float v = 0.f;
#pragma unroll
    for (int k2 = 0; k2 < 4; ++k2) v += res[t + 256 * k2];
#pragma unroll
    for (int off = 32; off; off >>= 1) v += __shfl_xor(v, off, 64);
    __shared__ float red[4];
    if ((t & 63) == 0) red[t >> 6] = v;
    __syncthreads();
    if (t == 0) out[0] = (red[0] + red[1] + red[2] + red[3]) * (1.0f / Bn);
}

extern "C" void kernel_launch(void* const* d_in, const int* in_sizes, int n_in,
                              void* d_out, int out_size, void* d_ws, size_t ws_size,
                              hipStream_t stream)
{
    const float* h     = (const float*)d_in[0];
    const int*   y     = (const int*)d_in[1];
    const float* trans = (const float*)d_in[3];
    float* out = (float*)d_out;
    float* res = (float*)d_ws;          // 1024 floats

    crf_all<<<Bn, 512, 0, stream>>>(h, y, trans, res);
    crf_final<<<1, 256, 0, stream>>>(res, out);
}